// Round 5
// baseline (80.984 us; speedup 1.0000x reference)
//
#include <hip/hip_runtime.h>

// Problem constants
#define NH 64
#define NW 64
#define ND 32
#define LTOT (NH * NW * ND)   // 131072

// Symmetric-pair formulation (exact, proven R2-R4):
//   loss * L = sum_{unordered in-bounds pairs} 2*k_pq*(1 - y0p*y0q - y1p*y1q)
//            + sum_p (147 - nh*nw*nd) * k_oob(p)
// C=2 softmax identity: y1 = 1 - y0  =>  (1 - y0p y0q - y1p y1q) = fma(y0q, 1-2*y0c, y0c).
// The y1 plane is never read.
// Each thread: 4 z-contiguous voxels x 2 (dh,dw) half-pairs (12 taps), float4 loads.
// 12 block-uniform subsets; sub 0 adds the lone (0,0,1) tap, sub 11 the OOB closed form.

__global__ __launch_bounds__(256, 8)
void gatedcrf3d_kernel(const float* __restrict__ y,       // (2, L) -- only plane 0 read
                       const float* __restrict__ sample,  // (1, L)
                       const float* __restrict__ spacing, // (3,)
                       float* __restrict__ out)           // (1,) pre-zeroed
{
    const int tid   = threadIdx.x;
    const int sub   = blockIdx.x >> 7;                     // 0..11, block-uniform
    const int group = ((blockIdx.x & 127) << 8) | tid;     // 0..32767
    const int h  = group >> 9;
    const int w  = (group >> 3) & 63;
    const int dg = group & 7;                              // z-group
    const int d0 = dg << 2;
    const int prow = (h << 11) + (w << 5);

    const float4* __restrict__ s4p = (const float4*)sample;
    const float4* __restrict__ y4p = (const float4*)y;

    constexpr float L2E  = 1.4426950408889634f;
    constexpr float NHL2 = -0.5f * L2E;

    const float sH = spacing[0] * 0.2f;
    const float sW = spacing[1] * 0.2f;
    const float sD = spacing[2] * 0.2f;
    const float nh2 = NHL2 * sH * sH;                      // -0.5*log2e folded in
    const float nw2 = NHL2 * sW * sW;
    const float nd2 = NHL2 * sD * sD;

    const float4 cs = s4p[(prow >> 2) + dg];
    const float4 cy = y4p[(prow >> 2) + dg];
    const float ic[4]  = {cs.x * 10.0f, cs.y * 10.0f, cs.z * 10.0f, cs.w * 10.0f};
    const float yc[4]  = {cy.x, cy.y, cy.z, cy.w};
    const float acv[4] = {__builtin_fmaf(-2.0f, cy.x, 1.0f), __builtin_fmaf(-2.0f, cy.y, 1.0f),
                          __builtin_fmaf(-2.0f, cy.z, 1.0f), __builtin_fmaf(-2.0f, cy.w, 1.0f)};

    float acc = 0.0f, extra = 0.0f;

    auto PB = [&](int dh, int dw) {                        // dh,dw literals
        const int hh = h + dh;                             // dh >= 0
        const int ww = w + dw;
        const bool ibhw = (hh < NH) & ((unsigned)ww < NW);
        const int hc = min(hh, NH - 1);
        const int wc = min(max(ww, 0), NW - 1);
        const int qb = (hc << 11) + (wc << 5);

        float sv[6], yv[6];
        const float4 fs = s4p[(qb >> 2) + dg];
        const float4 fy = y4p[(qb >> 2) + dg];
        sv[1] = fs.x; sv[2] = fs.y; sv[3] = fs.z; sv[4] = fs.w;
        yv[1] = fy.x; yv[2] = fy.y; yv[3] = fy.z; yv[4] = fy.w;
        const int im = qb + max(d0 - 1, 0);
        const int ip = qb + min(d0 + 4, ND - 1);
        sv[0] = sample[im]; sv[5] = sample[ip];
        yv[0] = y[im];      yv[5] = y[ip];

        const float spat0 = nh2 * (float)(dh * dh) + nw2 * (float)(dw * dw);
        const float spat1 = spat0 + nd2;

        #pragma unroll
        for (int j = 0; j < 4; ++j) {
            #pragma unroll
            for (int dd = -1; dd <= 1; ++dd) {
                bool val = ibhw;
                if (j == 0 && dd == -1) val = ibhw & (dg > 0);
                if (j == 3 && dd ==  1) val = ibhw & (dg < 7);
                const float sq = sv[1 + j + dd];
                const float yq = yv[1 + j + dd];
                const float di  = __builtin_fmaf(sq, 10.0f, -ic[j]);
                const float arg = __builtin_fmaf(di * NHL2, di, dd ? spat1 : spat0);
                const float k   = __builtin_exp2f(arg);
                const float t   = __builtin_fmaf(yq, acv[j], yc[j]);
                acc += val ? k * t : 0.0f;
            }
        }
    };

    switch (sub) {
      case  0: PB(0, 1); PB(0, 2); {
            // lone (0,0,1) half-offset along +z in the center row
            const int ip = prow + min(d0 + 4, ND - 1);
            const float s5 = sample[ip];
            const float y5 = y[ip];
            #pragma unroll
            for (int j = 0; j < 4; ++j) {
                const float di = (j < 3) ? (ic[j + 1] - ic[j])
                                         : __builtin_fmaf(s5, 10.0f, -ic[3]);
                const float yq = (j < 3) ? yc[j + 1] : y5;
                const bool val = (j < 3) ? true : (dg < 7);
                const float arg = __builtin_fmaf(di * NHL2, di, nd2);
                const float k   = __builtin_exp2f(arg);
                const float t   = __builtin_fmaf(yq, acv[j], yc[j]);
                acc += val ? k * t : 0.0f;
            }
        } break;
      case  1: PB(0,  3); PB(1, -3); break;
      case  2: PB(1, -2); PB(1, -1); break;
      case  3: PB(1,  0); PB(1,  1); break;
      case  4: PB(1,  2); PB(1,  3); break;
      case  5: PB(2, -3); PB(2, -2); break;
      case  6: PB(2, -1); PB(2,  0); break;
      case  7: PB(2,  1); PB(2,  2); break;
      case  8: PB(2,  3); PB(3, -3); break;
      case  9: PB(3, -2); PB(3, -1); break;
      case 10: PB(3,  0); PB(3,  1); break;
      case 11: PB(3,  2); PB(3,  3); {
            // out-of-bounds taps, closed form (zero-padded unfold)
            const int nhv = min(h, 3) + min(NH - 1 - h, 3) + 1;
            const int nwv = min(w, 3) + min(NW - 1 - w, 3) + 1;
            const float base = nh2 * (float)(h * h) + nw2 * (float)(w * w);
            #pragma unroll
            for (int j = 0; j < 4; ++j) {
                const int dj  = d0 + j;
                const int ndv = min(dj, 1) + min(ND - 1 - dj, 1) + 1;
                const int cnt = 147 - nhv * nwv * ndv;
                const float argo = __builtin_fmaf(nd2, (float)(dj * dj), base)
                                 + NHL2 * ic[j] * ic[j];
                extra += (float)cnt * __builtin_exp2f(argo);
            }
        } break;
    }

    float contrib = __builtin_fmaf(2.0f, acc, extra);

    // wave64 reduction -> LDS -> one atomic per block
    #pragma unroll
    for (int off = 32; off > 0; off >>= 1)
        contrib += __shfl_down(contrib, off, 64);

    __shared__ float red[4];
    if ((tid & 63) == 0) red[tid >> 6] = contrib;
    __syncthreads();
    if (tid == 0) {
        atomicAdd(out, (red[0] + red[1] + red[2] + red[3]) * (1.0f / (float)LTOT));
    }
}

extern "C" void kernel_launch(void* const* d_in, const int* in_sizes, int n_in,
                              void* d_out, int out_size, void* d_ws, size_t ws_size,
                              hipStream_t stream) {
    const float* y       = (const float*)d_in[0]; // y_hat_softmax (1,2,64,64,32)
    const float* sample  = (const float*)d_in[1]; // (1,1,64,64,32)
    const float* spacing = (const float*)d_in[2]; // (3,1)
    float* out = (float*)d_out;

    hipMemsetAsync(out, 0, sizeof(float), stream);

    gatedcrf3d_kernel<<<12 * 128, 256, 0, stream>>>(y, sample, spacing, out);
}

// Round 6
// 73.398 us; speedup vs baseline: 1.1034x; 1.1034x over previous
//
#include <hip/hip_runtime.h>

// Problem constants
#define NH 64
#define NW 64
#define ND 32
#define LTOT (NH * NW * ND)   // 131072

// Symmetric-pair formulation (exact, proven R2-R5):
//   loss * L = sum_{unordered in-bounds pairs, 7x7x3 nbhd} 2*k_pq*(1 - y0p*y0q - y1p*y1q)
//            + sum_p (147 - nh*nw*nd) * k_oob(p)
// C=2 softmax identity: y1 = 1-y0  =>  (1 - y0p y0q - y1p y1q) = fma(y0q, 1-2*y0c, y0c).
// The y1 plane is NEVER read (R4 structure + R5's identity, nothing else changed vs R4).
// 73 half-offsets = 24 (dh,dw) pairs x dd in {-1,0,1}  +  the lone (0,0,1).
// 8 wave-uniform subsets x 3 pairs; sub0 adds the lone tap, sub7 the OOB closed form.

__global__ __launch_bounds__(1024, 8)
void gatedcrf3d_kernel(const float* __restrict__ y,       // (2, L) -- only plane 0 read
                       const float* __restrict__ sample,  // (1, L)
                       const float* __restrict__ spacing, // (3,)
                       float* __restrict__ out)           // (1,) pre-zeroed
{
    const int tid = threadIdx.x;
    const int sub = tid >> 7;                    // 0..7, uniform per wave
    const int v   = tid & 127;                   // voxel slot in block

    const int h = blockIdx.x >> 4;               // provably scalar
    const int w = ((blockIdx.x & 15) << 2) + (v >> 5);
    const int d = v & 31;
    const int p = (h << 11) + (w << 5) + d;

    constexpr float L2E  = 1.4426950408889634f;  // log2(e)
    constexpr float NHL2 = -0.5f * L2E;

    const float sH = spacing[0] * 0.2f;          // / SIGMA_XY
    const float sW = spacing[1] * 0.2f;
    const float sD = spacing[2] * 0.2f;
    const float nh2 = NHL2 * sH * sH;            // -0.5*log2e pre-folded
    const float nw2 = NHL2 * sW * sW;
    const float nd2 = NHL2 * sD * sD;

    const float ic  = sample[p] * 10.0f;         // / SIGMA_IMG
    const float y0c = y[p];
    const float acv = __builtin_fmaf(-2.0f, y0c, 1.0f);   // 1 - 2*y0c

    const int  zm = max(d - 1, 0);
    const int  zp = min(d + 1, ND - 1);
    const bool vm = d > 0;
    const bool vp = d < ND - 1;

    float acc = 0.0f, extra = 0.0f;

    auto PB = [&](int dh, int dw) {              // dh,dw are literals -> const-folded
        const int hh = h + dh;                   // dh >= 0 always
        const int ww = w + dw;
        const bool ibhw = (hh < NH) & ((unsigned)ww < NW);
        const int hc = min(hh, NH - 1);
        const int wc = min(max(ww, 0), NW - 1);
        const int qb = (hc << 11) + (wc << 5);
        const float spat0 = nh2 * (float)(dh * dh) + nw2 * (float)(dw * dw);
        const float spat1 = spat0 + nd2;
        const int q0 = qb + zm, q1 = qb + d, q2 = qb + zp;
        // 6 loads per 3 taps (was 9 with the y1 plane)
        const float s0 = sample[q0], s1 = sample[q1], s2 = sample[q2];
        const float a0 = y[q0],      a1 = y[q1],      a2 = y[q2];

        float di, arg, k, t;
        di  = __builtin_fmaf(s0, 10.0f, -ic);
        arg = __builtin_fmaf(di * NHL2, di, spat1);
        k   = __builtin_exp2f(arg);
        t   = __builtin_fmaf(a0, acv, y0c);
        acc += (ibhw & vm) ? k * t : 0.0f;

        di  = __builtin_fmaf(s1, 10.0f, -ic);
        arg = __builtin_fmaf(di * NHL2, di, spat0);
        k   = __builtin_exp2f(arg);
        t   = __builtin_fmaf(a1, acv, y0c);
        acc += ibhw ? k * t : 0.0f;

        di  = __builtin_fmaf(s2, 10.0f, -ic);
        arg = __builtin_fmaf(di * NHL2, di, spat1);
        k   = __builtin_exp2f(arg);
        t   = __builtin_fmaf(a2, acv, y0c);
        acc += (ibhw & vp) ? k * t : 0.0f;
    };

    switch (sub) {
      case 0: PB(0,1); PB(0,2); PB(0,3); {
            // lone (0,0,1) half-offset
            const int q = (h << 11) + (w << 5) + zp;
            const float di  = __builtin_fmaf(sample[q], 10.0f, -ic);
            const float arg = __builtin_fmaf(di * NHL2, di, nd2);
            const float k   = __builtin_exp2f(arg);
            const float t   = __builtin_fmaf(y[q], acv, y0c);
            acc += vp ? k * t : 0.0f;
        } break;
      case 1: PB(1,-3); PB(1,-2); PB(1,-1); break;
      case 2: PB(1, 0); PB(1, 1); PB(1, 2); break;
      case 3: PB(1, 3); PB(2,-3); PB(2,-2); break;
      case 4: PB(2,-1); PB(2, 0); PB(2, 1); break;
      case 5: PB(2, 2); PB(2, 3); PB(3,-3); break;
      case 6: PB(3,-2); PB(3,-1); PB(3, 0); break;
      case 7: PB(3, 1); PB(3, 2); PB(3, 3); {
            // out-of-bounds taps, closed form (zero-padded unfold semantics)
            const int nhv = min(h, 3) + min(NH - 1 - h, 3) + 1;
            const int nwv = min(w, 3) + min(NW - 1 - w, 3) + 1;
            const int ndv = min(d, 1) + min(ND - 1 - d, 1) + 1;
            const int cnt = 147 - nhv * nwv * ndv;
            const float argo = nh2 * (float)(h * h) + nw2 * (float)(w * w)
                             + nd2 * (float)(d * d) + NHL2 * ic * ic;
            extra = (float)cnt * __builtin_exp2f(argo);
        } break;
    }

    float contrib = __builtin_fmaf(2.0f, acc, extra);

    // wave64 reduction -> LDS -> one atomic per block
    #pragma unroll
    for (int off = 32; off > 0; off >>= 1)
        contrib += __shfl_down(contrib, off, 64);

    __shared__ float red[16];
    if ((tid & 63) == 0) red[tid >> 6] = contrib;
    __syncthreads();
    if (tid == 0) {
        float s = 0.0f;
        #pragma unroll
        for (int i = 0; i < 16; ++i) s += red[i];
        atomicAdd(out, s * (1.0f / (float)LTOT));
    }
}

extern "C" void kernel_launch(void* const* d_in, const int* in_sizes, int n_in,
                              void* d_out, int out_size, void* d_ws, size_t ws_size,
                              hipStream_t stream) {
    const float* y       = (const float*)d_in[0]; // y_hat_softmax (1,2,64,64,32)
    const float* sample  = (const float*)d_in[1]; // (1,1,64,64,32)
    const float* spacing = (const float*)d_in[2]; // (3,1)
    float* out = (float*)d_out;

    hipMemsetAsync(out, 0, sizeof(float), stream);

    gatedcrf3d_kernel<<<LTOT / 128, 1024, 0, stream>>>(y, sample, spacing, out);
}

// Round 7
// 64.952 us; speedup vs baseline: 1.2468x; 1.1300x over previous
//
#include <hip/hip_runtime.h>

// Problem constants
#define NH 64
#define NW 64
#define ND 32
#define LTOT (NH * NW * ND)   // 131072
#define NBLK 1024             // main-kernel grid

// Symmetric-pair formulation (exact, proven R2-R6):
//   loss * L = sum_{unordered in-bounds pairs, 7x7x3 nbhd} 2*k_pq*(1 - y0p*y0q - y1p*y1q)
//            + sum_p (147 - nh*nw*nd) * k_oob(p)
// C=2 softmax identity: y1 = 1-y0  =>  (1 - y0p y0q - y1p y1q) = fma(y0q, 1-2*y0c, y0c).
// R7 change: NO single-address atomics. Block partials -> d_ws, tiny reduce kernel -> d_out.

__global__ __launch_bounds__(1024, 8)
void gatedcrf3d_kernel(const float* __restrict__ y,       // (2, L) -- only plane 0 read
                       const float* __restrict__ sample,  // (1, L)
                       const float* __restrict__ spacing, // (3,)
                       float* __restrict__ partial)       // (NBLK,)
{
    const int tid = threadIdx.x;
    const int sub = tid >> 7;                    // 0..7, uniform per wave
    const int v   = tid & 127;                   // voxel slot in block

    const int h = blockIdx.x >> 4;               // provably scalar
    const int w = ((blockIdx.x & 15) << 2) + (v >> 5);
    const int d = v & 31;
    const int p = (h << 11) + (w << 5) + d;

    constexpr float L2E  = 1.4426950408889634f;  // log2(e)
    constexpr float NHL2 = -0.5f * L2E;

    const float sH = spacing[0] * 0.2f;          // / SIGMA_XY
    const float sW = spacing[1] * 0.2f;
    const float sD = spacing[2] * 0.2f;
    const float nh2 = NHL2 * sH * sH;            // -0.5*log2e pre-folded
    const float nw2 = NHL2 * sW * sW;
    const float nd2 = NHL2 * sD * sD;

    const float ic  = sample[p] * 10.0f;         // / SIGMA_IMG
    const float y0c = y[p];
    const float acv = __builtin_fmaf(-2.0f, y0c, 1.0f);   // 1 - 2*y0c

    const int  zm = max(d - 1, 0);
    const int  zp = min(d + 1, ND - 1);
    const bool vm = d > 0;
    const bool vp = d < ND - 1;

    float acc = 0.0f, extra = 0.0f;

    auto PB = [&](int dh, int dw) {              // dh,dw are literals -> const-folded
        const int hh = h + dh;                   // dh >= 0 always
        const int ww = w + dw;
        const bool ibhw = (hh < NH) & ((unsigned)ww < NW);
        const int hc = min(hh, NH - 1);
        const int wc = min(max(ww, 0), NW - 1);
        const int qb = (hc << 11) + (wc << 5);
        const float spat0 = nh2 * (float)(dh * dh) + nw2 * (float)(dw * dw);
        const float spat1 = spat0 + nd2;
        const int q0 = qb + zm, q1 = qb + d, q2 = qb + zp;
        const float s0 = sample[q0], s1 = sample[q1], s2 = sample[q2];
        const float a0 = y[q0],      a1 = y[q1],      a2 = y[q2];

        float di, arg, k, t;
        di  = __builtin_fmaf(s0, 10.0f, -ic);
        arg = __builtin_fmaf(di * NHL2, di, spat1);
        k   = __builtin_exp2f(arg);
        t   = __builtin_fmaf(a0, acv, y0c);
        acc += (ibhw & vm) ? k * t : 0.0f;

        di  = __builtin_fmaf(s1, 10.0f, -ic);
        arg = __builtin_fmaf(di * NHL2, di, spat0);
        k   = __builtin_exp2f(arg);
        t   = __builtin_fmaf(a1, acv, y0c);
        acc += ibhw ? k * t : 0.0f;

        di  = __builtin_fmaf(s2, 10.0f, -ic);
        arg = __builtin_fmaf(di * NHL2, di, spat1);
        k   = __builtin_exp2f(arg);
        t   = __builtin_fmaf(a2, acv, y0c);
        acc += (ibhw & vp) ? k * t : 0.0f;
    };

    switch (sub) {
      case 0: PB(0,1); PB(0,2); PB(0,3); {
            // lone (0,0,1) half-offset
            const int q = (h << 11) + (w << 5) + zp;
            const float di  = __builtin_fmaf(sample[q], 10.0f, -ic);
            const float arg = __builtin_fmaf(di * NHL2, di, nd2);
            const float k   = __builtin_exp2f(arg);
            const float t   = __builtin_fmaf(y[q], acv, y0c);
            acc += vp ? k * t : 0.0f;
        } break;
      case 1: PB(1,-3); PB(1,-2); PB(1,-1); break;
      case 2: PB(1, 0); PB(1, 1); PB(1, 2); break;
      case 3: PB(1, 3); PB(2,-3); PB(2,-2); break;
      case 4: PB(2,-1); PB(2, 0); PB(2, 1); break;
      case 5: PB(2, 2); PB(2, 3); PB(3,-3); break;
      case 6: PB(3,-2); PB(3,-1); PB(3, 0); break;
      case 7: PB(3, 1); PB(3, 2); PB(3, 3); {
            // out-of-bounds taps, closed form (zero-padded unfold semantics)
            const int nhv = min(h, 3) + min(NH - 1 - h, 3) + 1;
            const int nwv = min(w, 3) + min(NW - 1 - w, 3) + 1;
            const int ndv = min(d, 1) + min(ND - 1 - d, 1) + 1;
            const int cnt = 147 - nhv * nwv * ndv;
            const float argo = nh2 * (float)(h * h) + nw2 * (float)(w * w)
                             + nd2 * (float)(d * d) + NHL2 * ic * ic;
            extra = (float)cnt * __builtin_exp2f(argo);
        } break;
    }

    float contrib = __builtin_fmaf(2.0f, acc, extra);

    // wave64 reduction -> LDS -> ONE PLAIN STORE per block (no atomics)
    #pragma unroll
    for (int off = 32; off > 0; off >>= 1)
        contrib += __shfl_down(contrib, off, 64);

    __shared__ float red[16];
    if ((tid & 63) == 0) red[tid >> 6] = contrib;
    __syncthreads();
    if (tid == 0) {
        float s = 0.0f;
        #pragma unroll
        for (int i = 0; i < 16; ++i) s += red[i];
        partial[blockIdx.x] = s;
    }
}

// Final reduce: 1 block, 256 threads, float4 over 1024 partials.
__global__ __launch_bounds__(256)
void reduce_kernel(const float4* __restrict__ partial4, float* __restrict__ out)
{
    const int tid = threadIdx.x;
    const float4 f = partial4[tid];
    float s = (f.x + f.y) + (f.z + f.w);

    #pragma unroll
    for (int off = 32; off > 0; off >>= 1)
        s += __shfl_down(s, off, 64);

    __shared__ float red[4];
    if ((tid & 63) == 0) red[tid >> 6] = s;
    __syncthreads();
    if (tid == 0)
        out[0] = (red[0] + red[1] + red[2] + red[3]) * (1.0f / (float)LTOT);
}

extern "C" void kernel_launch(void* const* d_in, const int* in_sizes, int n_in,
                              void* d_out, int out_size, void* d_ws, size_t ws_size,
                              hipStream_t stream) {
    const float* y       = (const float*)d_in[0]; // y_hat_softmax (1,2,64,64,32)
    const float* sample  = (const float*)d_in[1]; // (1,1,64,64,32)
    const float* spacing = (const float*)d_in[2]; // (3,1)
    float* out     = (float*)d_out;
    float* partial = (float*)d_ws;                // NBLK floats

    gatedcrf3d_kernel<<<NBLK, 1024, 0, stream>>>(y, sample, spacing, partial);
    reduce_kernel<<<1, 256, 0, stream>>>((const float4*)partial, out);
}

// Round 8
// 64.413 us; speedup vs baseline: 1.2573x; 1.0084x over previous
//
#include <hip/hip_runtime.h>

// Problem constants
#define NH 64
#define NW 64
#define ND 32
#define LTOT (NH * NW * ND)   // 131072
#define NBLK 512              // main-kernel grid

// Symmetric-pair formulation (exact, proven R2-R7):
//   loss * L = sum_{unordered in-bounds pairs, 7x7x3 nbhd} 2*k_pq*(1 - y0p*y0q - y1p*y1q)
//            + sum_p (147 - nh*nw*nd) * k_oob(p)
// C=2 softmax identity: y1 = 1-y0  =>  (1 - y0p y0q - y1p y1q) = fma(y0q, 1-2*y0c, y0c).
// No atomics (R7 win). R8: 512 blocks x 1024 thr, 4 wave-uniform subsets x 6 pairs
// (~18 taps/thread) -- halves per-thread fixed overhead; 8192 waves = exactly 32/CU.

__global__ __launch_bounds__(1024, 8)
void gatedcrf3d_kernel(const float* __restrict__ y,       // (2, L) -- only plane 0 read
                       const float* __restrict__ sample,  // (1, L)
                       const float* __restrict__ spacing, // (3,)
                       float* __restrict__ partial)       // (NBLK,)
{
    const int tid = threadIdx.x;
    const int sub = tid >> 8;                    // 0..3, uniform per 4-wave group
    const int v   = tid & 255;                   // voxel slot in block (256 voxels)

    const int h = blockIdx.x >> 3;               // provably scalar
    const int w = ((blockIdx.x & 7) << 3) + (v >> 5);
    const int d = v & 31;
    const int p = (h << 11) + (w << 5) + d;

    constexpr float L2E  = 1.4426950408889634f;  // log2(e)
    constexpr float NHL2 = -0.5f * L2E;

    const float sH = spacing[0] * 0.2f;          // / SIGMA_XY
    const float sW = spacing[1] * 0.2f;
    const float sD = spacing[2] * 0.2f;
    const float nh2 = NHL2 * sH * sH;            // -0.5*log2e pre-folded
    const float nw2 = NHL2 * sW * sW;
    const float nd2 = NHL2 * sD * sD;

    const float ic  = sample[p] * 10.0f;         // / SIGMA_IMG
    const float y0c = y[p];
    const float acv = __builtin_fmaf(-2.0f, y0c, 1.0f);   // 1 - 2*y0c

    const int  zm = max(d - 1, 0);
    const int  zp = min(d + 1, ND - 1);
    const bool vm = d > 0;
    const bool vp = d < ND - 1;

    float acc = 0.0f, extra = 0.0f;

    auto PB = [&](int dh, int dw) {              // dh,dw are literals -> const-folded
        const int hh = h + dh;                   // dh >= 0 always
        const int ww = w + dw;
        const bool ibhw = (hh < NH) & ((unsigned)ww < NW);
        const int hc = min(hh, NH - 1);
        const int wc = min(max(ww, 0), NW - 1);
        const int qb = (hc << 11) + (wc << 5);
        const float spat0 = nh2 * (float)(dh * dh) + nw2 * (float)(dw * dw);
        const float spat1 = spat0 + nd2;
        const int q0 = qb + zm, q1 = qb + d, q2 = qb + zp;
        const float s0 = sample[q0], s1 = sample[q1], s2 = sample[q2];
        const float a0 = y[q0],      a1 = y[q1],      a2 = y[q2];

        float di, arg, k, t;
        di  = __builtin_fmaf(s0, 10.0f, -ic);
        arg = __builtin_fmaf(di * NHL2, di, spat1);
        k   = __builtin_exp2f(arg);
        t   = __builtin_fmaf(a0, acv, y0c);
        acc += (ibhw & vm) ? k * t : 0.0f;

        di  = __builtin_fmaf(s1, 10.0f, -ic);
        arg = __builtin_fmaf(di * NHL2, di, spat0);
        k   = __builtin_exp2f(arg);
        t   = __builtin_fmaf(a1, acv, y0c);
        acc += ibhw ? k * t : 0.0f;

        di  = __builtin_fmaf(s2, 10.0f, -ic);
        arg = __builtin_fmaf(di * NHL2, di, spat1);
        k   = __builtin_exp2f(arg);
        t   = __builtin_fmaf(a2, acv, y0c);
        acc += (ibhw & vp) ? k * t : 0.0f;
    };

    switch (sub) {
      case 0: PB(0,1); PB(0,2); PB(0,3); PB(1,-3); PB(1,-2); PB(1,-1); {
            // lone (0,0,1) half-offset
            const int q = (h << 11) + (w << 5) + zp;
            const float di  = __builtin_fmaf(sample[q], 10.0f, -ic);
            const float arg = __builtin_fmaf(di * NHL2, di, nd2);
            const float k   = __builtin_exp2f(arg);
            const float t   = __builtin_fmaf(y[q], acv, y0c);
            acc += vp ? k * t : 0.0f;
        } break;
      case 1: PB(1, 0); PB(1, 1); PB(1, 2); PB(1, 3); PB(2,-3); PB(2,-2); break;
      case 2: PB(2,-1); PB(2, 0); PB(2, 1); PB(2, 2); PB(2, 3); PB(3,-3); break;
      case 3: PB(3,-2); PB(3,-1); PB(3, 0); PB(3, 1); PB(3, 2); PB(3, 3); {
            // out-of-bounds taps, closed form (zero-padded unfold semantics)
            const int nhv = min(h, 3) + min(NH - 1 - h, 3) + 1;
            const int nwv = min(w, 3) + min(NW - 1 - w, 3) + 1;
            const int ndv = min(d, 1) + min(ND - 1 - d, 1) + 1;
            const int cnt = 147 - nhv * nwv * ndv;
            const float argo = nh2 * (float)(h * h) + nw2 * (float)(w * w)
                             + nd2 * (float)(d * d) + NHL2 * ic * ic;
            extra = (float)cnt * __builtin_exp2f(argo);
        } break;
    }

    float contrib = __builtin_fmaf(2.0f, acc, extra);

    // wave64 reduction -> LDS -> ONE PLAIN STORE per block (no atomics)
    #pragma unroll
    for (int off = 32; off > 0; off >>= 1)
        contrib += __shfl_down(contrib, off, 64);

    __shared__ float red[16];
    if ((tid & 63) == 0) red[tid >> 6] = contrib;
    __syncthreads();
    if (tid == 0) {
        float s = 0.0f;
        #pragma unroll
        for (int i = 0; i < 16; ++i) s += red[i];
        partial[blockIdx.x] = s;
    }
}

// Final reduce: 1 block, 128 threads, one float4 each over 512 partials.
__global__ __launch_bounds__(128)
void reduce_kernel(const float4* __restrict__ partial4, float* __restrict__ out)
{
    const int tid = threadIdx.x;
    const float4 f = partial4[tid];
    float s = (f.x + f.y) + (f.z + f.w);

    #pragma unroll
    for (int off = 32; off > 0; off >>= 1)
        s += __shfl_down(s, off, 64);

    __shared__ float red[2];
    if ((tid & 63) == 0) red[tid >> 6] = s;
    __syncthreads();
    if (tid == 0)
        out[0] = (red[0] + red[1]) * (1.0f / (float)LTOT);
}

extern "C" void kernel_launch(void* const* d_in, const int* in_sizes, int n_in,
                              void* d_out, int out_size, void* d_ws, size_t ws_size,
                              hipStream_t stream) {
    const float* y       = (const float*)d_in[0]; // y_hat_softmax (1,2,64,64,32)
    const float* sample  = (const float*)d_in[1]; // (1,1,64,64,32)
    const float* spacing = (const float*)d_in[2]; // (3,1)
    float* out     = (float*)d_out;
    float* partial = (float*)d_ws;                // NBLK floats

    gatedcrf3d_kernel<<<NBLK, 1024, 0, stream>>>(y, sample, spacing, partial);
    reduce_kernel<<<1, 128, 0, stream>>>((const float4*)partial, out);
}

// Round 9
// 63.958 us; speedup vs baseline: 1.2662x; 1.0071x over previous
//
#include <hip/hip_runtime.h>

// Problem constants
#define NH 64
#define NW 64
#define ND 32
#define LTOT (NH * NW * ND)   // 131072
#define NBLK 512              // main-kernel grid

// Symmetric-pair formulation (exact, proven R2-R8):
//   loss * L = sum_{unordered in-bounds pairs, 7x7x3 nbhd} 2*k_pq*(1 - y0p*y0q - y1p*y1q)
//            + sum_p (147 - nh*nw*nd) * k_oob(p)
// C=2 softmax identity: y1 = 1-y0  =>  (1 - y0p y0q - y1p y1q) = fma(y0q, 1-2*y0c, y0c).
// No atomics (R7). 512 blocks x 1024 thr, 4 wave-uniform subsets x 6 pairs (R8).
// R9: interior-block fast path (348/512 blocks skip all h/w bounds logic),
// fma-accumulate on always-valid taps, single-wave reduce kernel.

__global__ __launch_bounds__(1024, 8)
void gatedcrf3d_kernel(const float* __restrict__ y,       // (2, L) -- only plane 0 read
                       const float* __restrict__ sample,  // (1, L)
                       const float* __restrict__ spacing, // (3,)
                       float* __restrict__ partial)       // (NBLK,)
{
    const int tid = threadIdx.x;
    const int sub = tid >> 8;                    // 0..3, uniform per 4-wave group
    const int v   = tid & 255;                   // voxel slot in block (256 voxels)

    const int h  = blockIdx.x >> 3;              // provably scalar
    const int wt = blockIdx.x & 7;               // w-tile, scalar
    const int w  = (wt << 3) + (v >> 5);
    const int d  = v & 31;
    const int p  = (h << 11) + (w << 5) + d;

    constexpr float L2E  = 1.4426950408889634f;  // log2(e)
    constexpr float NHL2 = -0.5f * L2E;

    const float sH = spacing[0] * 0.2f;          // / SIGMA_XY
    const float sW = spacing[1] * 0.2f;
    const float sD = spacing[2] * 0.2f;
    const float nh2 = NHL2 * sH * sH;            // -0.5*log2e pre-folded
    const float nw2 = NHL2 * sW * sW;
    const float nd2 = NHL2 * sD * sD;

    const float ic  = sample[p] * 10.0f;         // / SIGMA_IMG
    const float y0c = y[p];
    const float acv = __builtin_fmaf(-2.0f, y0c, 1.0f);   // 1 - 2*y0c

    const int  zm = max(d - 1, 0);
    const int  zp = min(d + 1, ND - 1);
    const bool vm = d > 0;
    const bool vp = d < ND - 1;

    float acc = 0.0f, extra = 0.0f;

    // Boundary path: full clamps + per-tap validity (R8-proven).
    auto PB = [&](int dh, int dw) {              // dh,dw literals -> const-folded
        const int hh = h + dh;                   // dh >= 0 always
        const int ww = w + dw;
        const bool ibhw = (hh < NH) & ((unsigned)ww < NW);
        const int hc = min(hh, NH - 1);
        const int wc = min(max(ww, 0), NW - 1);
        const int qb = (hc << 11) + (wc << 5);
        const float spat0 = nh2 * (float)(dh * dh) + nw2 * (float)(dw * dw);
        const float spat1 = spat0 + nd2;
        const int q0 = qb + zm, q1 = qb + d, q2 = qb + zp;
        const float s0 = sample[q0], s1 = sample[q1], s2 = sample[q2];
        const float a0 = y[q0],      a1 = y[q1],      a2 = y[q2];

        float di, arg, k, t;
        di  = __builtin_fmaf(s0, 10.0f, -ic);
        arg = __builtin_fmaf(di * NHL2, di, spat1);
        k   = __builtin_exp2f(arg);
        t   = __builtin_fmaf(a0, acv, y0c);
        acc += (ibhw & vm) ? k * t : 0.0f;

        di  = __builtin_fmaf(s1, 10.0f, -ic);
        arg = __builtin_fmaf(di * NHL2, di, spat0);
        k   = __builtin_exp2f(arg);
        t   = __builtin_fmaf(a1, acv, y0c);
        acc += ibhw ? k * t : 0.0f;

        di  = __builtin_fmaf(s2, 10.0f, -ic);
        arg = __builtin_fmaf(di * NHL2, di, spat1);
        k   = __builtin_exp2f(arg);
        t   = __builtin_fmaf(a2, acv, y0c);
        acc += (ibhw & vp) ? k * t : 0.0f;
    };

    // Interior path: no h/w bounds logic at all; only z-edge selects remain.
    auto PBI = [&](int dh, int dw) {
        const int qb = ((h + dh) << 11) + ((w + dw) << 5);
        const float spat0 = nh2 * (float)(dh * dh) + nw2 * (float)(dw * dw);
        const float spat1 = spat0 + nd2;
        const int q0 = qb + zm, q1 = qb + d, q2 = qb + zp;
        const float s0 = sample[q0], s1 = sample[q1], s2 = sample[q2];
        const float a0 = y[q0],      a1 = y[q1],      a2 = y[q2];

        float di, arg, k, t;
        di  = __builtin_fmaf(s0, 10.0f, -ic);
        arg = __builtin_fmaf(di * NHL2, di, spat1);
        k   = __builtin_exp2f(arg);
        t   = __builtin_fmaf(a0, acv, y0c);
        acc += vm ? k * t : 0.0f;

        di  = __builtin_fmaf(s1, 10.0f, -ic);
        arg = __builtin_fmaf(di * NHL2, di, spat0);
        k   = __builtin_exp2f(arg);
        t   = __builtin_fmaf(a1, acv, y0c);
        acc = __builtin_fmaf(k, t, acc);         // always valid: single fmac

        di  = __builtin_fmaf(s2, 10.0f, -ic);
        arg = __builtin_fmaf(di * NHL2, di, spat1);
        k   = __builtin_exp2f(arg);
        t   = __builtin_fmaf(a2, acv, y0c);
        acc += vp ? k * t : 0.0f;
    };

    const bool interior = (h <= NH - 1 - 3) & (wt >= 1) & (wt <= 6);

    if (interior) {
        switch (sub) {
          case 0: PBI(0,1); PBI(0,2); PBI(0,3); PBI(1,-3); PBI(1,-2); PBI(1,-1); break;
          case 1: PBI(1,0); PBI(1,1); PBI(1,2); PBI(1,3);  PBI(2,-3); PBI(2,-2); break;
          case 2: PBI(2,-1); PBI(2,0); PBI(2,1); PBI(2,2); PBI(2,3);  PBI(3,-3); break;
          case 3: PBI(3,-2); PBI(3,-1); PBI(3,0); PBI(3,1); PBI(3,2); PBI(3,3);  break;
        }
    } else {
        switch (sub) {
          case 0: PB(0,1); PB(0,2); PB(0,3); PB(1,-3); PB(1,-2); PB(1,-1); break;
          case 1: PB(1,0); PB(1,1); PB(1,2); PB(1,3);  PB(2,-3); PB(2,-2); break;
          case 2: PB(2,-1); PB(2,0); PB(2,1); PB(2,2); PB(2,3);  PB(3,-3); break;
          case 3: PB(3,-2); PB(3,-1); PB(3,0); PB(3,1); PB(3,2); PB(3,3);  break;
        }
    }

    if (sub == 0) {
        // lone (0,0,1) half-offset (center row always in-bounds in h/w)
        const int q = (h << 11) + (w << 5) + zp;
        const float di  = __builtin_fmaf(sample[q], 10.0f, -ic);
        const float arg = __builtin_fmaf(di * NHL2, di, nd2);
        const float k   = __builtin_exp2f(arg);
        const float t   = __builtin_fmaf(y[q], acv, y0c);
        acc += vp ? k * t : 0.0f;
    } else if (sub == 3) {
        // out-of-bounds taps, closed form (zero-padded unfold semantics)
        const int nhv = min(h, 3) + min(NH - 1 - h, 3) + 1;
        const int nwv = min(w, 3) + min(NW - 1 - w, 3) + 1;
        const int ndv = min(d, 1) + min(ND - 1 - d, 1) + 1;
        const int cnt = 147 - nhv * nwv * ndv;
        const float argo = nh2 * (float)(h * h) + nw2 * (float)(w * w)
                         + nd2 * (float)(d * d) + NHL2 * ic * ic;
        extra = (float)cnt * __builtin_exp2f(argo);
    }

    float contrib = __builtin_fmaf(2.0f, acc, extra);

    // wave64 reduction -> LDS -> ONE PLAIN STORE per block (no atomics)
    #pragma unroll
    for (int off = 32; off > 0; off >>= 1)
        contrib += __shfl_down(contrib, off, 64);

    __shared__ float red[16];
    if ((tid & 63) == 0) red[tid >> 6] = contrib;
    __syncthreads();
    if (tid == 0) {
        float s = 0.0f;
        #pragma unroll
        for (int i = 0; i < 16; ++i) s += red[i];
        partial[blockIdx.x] = s;
    }
}

// Final reduce: ONE wave, 2 float4 per lane over 512 partials; no LDS, no barrier.
__global__ __launch_bounds__(64)
void reduce_kernel(const float4* __restrict__ partial4, float* __restrict__ out)
{
    const int tid = threadIdx.x;
    const float4 a = partial4[tid];
    const float4 b = partial4[tid + 64];
    float s = ((a.x + a.y) + (a.z + a.w)) + ((b.x + b.y) + (b.z + b.w));

    #pragma unroll
    for (int off = 32; off > 0; off >>= 1)
        s += __shfl_down(s, off, 64);

    if (tid == 0)
        out[0] = s * (1.0f / (float)LTOT);
}

extern "C" void kernel_launch(void* const* d_in, const int* in_sizes, int n_in,
                              void* d_out, int out_size, void* d_ws, size_t ws_size,
                              hipStream_t stream) {
    const float* y       = (const float*)d_in[0]; // y_hat_softmax (1,2,64,64,32)
    const float* sample  = (const float*)d_in[1]; // (1,1,64,64,32)
    const float* spacing = (const float*)d_in[2]; // (3,1)
    float* out     = (float*)d_out;
    float* partial = (float*)d_ws;                // NBLK floats

    gatedcrf3d_kernel<<<NBLK, 1024, 0, stream>>>(y, sample, spacing, partial);
    reduce_kernel<<<1, 64, 0, stream>>>((const float4*)partial, out);
}